// Round 1
// baseline (1042.952 us; speedup 1.0000x reference)
//
#include <hip/hip_runtime.h>
#include <hip/hip_bf16.h>

#define HW 4096
#define NC 512
#define NB 4

typedef float f32x4 __attribute__((ext_vector_type(4)));
typedef short bf16x8 __attribute__((ext_vector_type(8)));

__device__ __forceinline__ unsigned short f2bf(float f){
  unsigned int u = __builtin_bit_cast(unsigned int, f);
  u += 0x7FFFu + ((u >> 16) & 1u);
  return (unsigned short)(u >> 16);
}
__device__ __forceinline__ float bf2f(unsigned short h){
  unsigned int u = ((unsigned int)h) << 16;
  return __builtin_bit_cast(float, u);
}

// ---------------- projection: q/k (hi+lo split, transposed) + v ----------------
// grid (32 itiles x 10 rowgroups x B), block 256.
// rowgroup 0 -> Wq rows 0..63, 1 -> Wk, 2..9 -> Wv rows (rg-2)*64..
__global__ __launch_bounds__(256) void proj_kernel(
    const float* __restrict__ x,
    const float* __restrict__ Wq, const float* __restrict__ bq,
    const float* __restrict__ Wk, const float* __restrict__ bk,
    const float* __restrict__ Wv, const float* __restrict__ bv,
    unsigned short* __restrict__ qhi, unsigned short* __restrict__ qlo,
    unsigned short* __restrict__ khi, unsigned short* __restrict__ klo,
    unsigned short* __restrict__ vv)
{
  const int it = blockIdx.x;       // 128 pixels per block
  const int rg = blockIdx.y;
  const int b  = blockIdx.z;
  const int i0 = it * 128;
  const int tid = threadIdx.x;
  const int ix = tid & 63;
  const int rq = tid >> 6;

  __shared__ float xs[16][129];
  __shared__ float ts[128][65];

  const float* W; const float* bias; int rbase;
  if (rg == 0)      { W = Wq; bias = bq; rbase = 0; }
  else if (rg == 1) { W = Wk; bias = bk; rbase = 0; }
  else              { W = Wv; bias = bv; rbase = (rg - 2) * 64; }

  float acc0[16], acc1[16];
  #pragma unroll
  for (int rr = 0; rr < 16; rr++){ acc0[rr] = 0.f; acc1[rr] = 0.f; }

  for (int c0 = 0; c0 < NC; c0 += 16){
    __syncthreads();
    #pragma unroll
    for (int u = 0; u < 8; u++){
      int idx = u * 256 + tid;
      int row = idx >> 7, col = idx & 127;
      xs[row][col] = x[((long)b * NC + c0 + row) * HW + i0 + col];
    }
    __syncthreads();
    float xq0[16], xq1[16];
    #pragma unroll
    for (int cc = 0; cc < 16; cc++){ xq0[cc] = xs[cc][ix]; xq1[cc] = xs[cc][ix + 64]; }
    #pragma unroll
    for (int rr = 0; rr < 16; rr++){
      const float* wrow = W + (long)(rbase + rq * 16 + rr) * NC + c0;
      #pragma unroll
      for (int q4 = 0; q4 < 4; q4++){
        f32x4 wv = *reinterpret_cast<const f32x4*>(wrow + q4 * 4);
        #pragma unroll
        for (int e = 0; e < 4; e++){
          acc0[rr] = fmaf(wv[e], xq0[q4 * 4 + e], acc0[rr]);
          acc1[rr] = fmaf(wv[e], xq1[q4 * 4 + e], acc1[rr]);
        }
      }
    }
  }

  if (rg >= 2){
    // v rows, natural [b][c][pix] layout, coalesced bf16 stores
    #pragma unroll
    for (int rr = 0; rr < 16; rr++){
      int r = rq * 16 + rr;
      float bb = bias[rbase + r];
      long base = ((long)b * NC + rbase + r) * HW + i0;
      vv[base + ix]      = f2bf(acc0[rr] + bb);
      vv[base + 64 + ix] = f2bf(acc1[rr] + bb);
    }
  } else {
    // q/k: transpose through LDS, split into bf16 hi + lo, store [b][pix][64]
    __syncthreads();
    #pragma unroll
    for (int rr = 0; rr < 16; rr++){
      int r = rq * 16 + rr;
      float bb = bias[r];
      ts[ix][r]      = acc0[rr] + bb;
      ts[ix + 64][r] = acc1[rr] + bb;
    }
    __syncthreads();
    unsigned short* hi = (rg == 0) ? qhi : khi;
    unsigned short* lo = (rg == 0) ? qlo : klo;
    #pragma unroll
    for (int u = 0; u < 32; u++){
      int il = rq * 32 + u;
      float v = ts[il][ix];
      unsigned short h = f2bf(v);
      float rem = v - bf2f(h);
      hi[((long)b * HW + i0 + il) * 64 + ix] = h;
      lo[((long)b * HW + i0 + il) * 64 + ix] = f2bf(rem);
    }
  }
}

// ---------------- flash attention ----------------
// grid (B*128) blocks, block = 256 (4 waves). Block covers 32 query rows.
// wave w: ig = w>>1 picks 16-row half, ch = w&1 picks 256-channel half of V.
__global__ __launch_bounds__(256, 2) void attn_kernel(
    const unsigned short* __restrict__ qhi, const unsigned short* __restrict__ qlo,
    const unsigned short* __restrict__ khi, const unsigned short* __restrict__ klo,
    const unsigned short* __restrict__ vv, unsigned short* __restrict__ Ot)
{
  const int bx = blockIdx.x;
  const int b  = bx >> 7;
  const int it = bx & 127;
  const int tid = threadIdx.x;
  const int w = tid >> 6;
  const int lane = tid & 63;
  const int g = lane >> 4, n = lane & 15;
  const int ig = w >> 1, ch = w & 1;
  const int i0 = it * 32 + ig * 16;
  const int c0w = ch * 256;

  __shared__ float ps_all[4][16][68];
  float (*ps)[68] = ps_all[w];

  // Q fragments (A-operand): row = lane&15, k = 32*ks + 8*(lane>>4) + e
  bf16x8 aqh[2], aql[2];
  {
    long qb = ((long)b * HW + i0 + n) * 64 + g * 8;
    aqh[0] = *reinterpret_cast<const bf16x8*>(qhi + qb);
    aqh[1] = *reinterpret_cast<const bf16x8*>(qhi + qb + 32);
    aql[0] = *reinterpret_cast<const bf16x8*>(qlo + qb);
    aql[1] = *reinterpret_cast<const bf16x8*>(qlo + qb + 32);
  }

  f32x4 acc[16];
  #pragma unroll
  for (int t = 0; t < 16; t++) acc[t] = (f32x4){0.f, 0.f, 0.f, 0.f};
  float mrow[4], lrow[4];
  #pragma unroll
  for (int r = 0; r < 4; r++){ mrow[r] = -1e30f; lrow[r] = 0.f; }

  for (int jt = 0; jt < 64; jt++){
    const int j0 = jt * 64;
    // S = Q^T K  (3-term hi/lo for fp32-grade logits)
    f32x4 s[4];
    #pragma unroll
    for (int nt = 0; nt < 4; nt++){
      long kb = ((long)b * HW + j0 + nt * 16 + n) * 64 + g * 8;
      bf16x8 bh0 = *reinterpret_cast<const bf16x8*>(khi + kb);
      bf16x8 bh1 = *reinterpret_cast<const bf16x8*>(khi + kb + 32);
      bf16x8 bl0 = *reinterpret_cast<const bf16x8*>(klo + kb);
      bf16x8 bl1 = *reinterpret_cast<const bf16x8*>(klo + kb + 32);
      f32x4 sv = (f32x4){0.f, 0.f, 0.f, 0.f};
      sv = __builtin_amdgcn_mfma_f32_16x16x32_bf16(aqh[0], bh0, sv, 0, 0, 0);
      sv = __builtin_amdgcn_mfma_f32_16x16x32_bf16(aqh[1], bh1, sv, 0, 0, 0);
      sv = __builtin_amdgcn_mfma_f32_16x16x32_bf16(aql[0], bh0, sv, 0, 0, 0);
      sv = __builtin_amdgcn_mfma_f32_16x16x32_bf16(aql[1], bh1, sv, 0, 0, 0);
      sv = __builtin_amdgcn_mfma_f32_16x16x32_bf16(aqh[0], bl0, sv, 0, 0, 0);
      sv = __builtin_amdgcn_mfma_f32_16x16x32_bf16(aqh[1], bl1, sv, 0, 0, 0);
      s[nt] = sv;
    }
    // online softmax: D-layout row = g*4+r, cols across the 16 lanes of the group
    float mnew[4]; int upd = 0;
    #pragma unroll
    for (int r = 0; r < 4; r++){
      float t = fmaxf(fmaxf(s[0][r], s[1][r]), fmaxf(s[2][r], s[3][r]));
      t = fmaxf(t, __shfl_xor(t, 1));
      t = fmaxf(t, __shfl_xor(t, 2));
      t = fmaxf(t, __shfl_xor(t, 4));
      t = fmaxf(t, __shfl_xor(t, 8));
      mnew[r] = fmaxf(mrow[r], t);
      upd |= (mnew[r] > mrow[r]) ? 1 : 0;
    }
    if (__any(upd)){
      #pragma unroll
      for (int r = 0; r < 4; r++){
        float sc = __expf(mrow[r] - mnew[r]);
        lrow[r] *= sc;
        mrow[r] = mnew[r];
        #pragma unroll
        for (int t = 0; t < 16; t++) acc[t][r] *= sc;
      }
    }
    float p[4][4];
    #pragma unroll
    for (int nt = 0; nt < 4; nt++)
      #pragma unroll
      for (int r = 0; r < 4; r++)
        p[nt][r] = __expf(s[nt][r] - mrow[r]);
    #pragma unroll
    for (int r = 0; r < 4; r++){
      float rs = (p[0][r] + p[1][r]) + (p[2][r] + p[3][r]);
      rs += __shfl_xor(rs, 1);
      rs += __shfl_xor(rs, 2);
      rs += __shfl_xor(rs, 4);
      rs += __shfl_xor(rs, 8);
      lrow[r] += rs;
    }
    // P tile -> per-wave LDS (fp32), re-read in A-fragment layout
    #pragma unroll
    for (int nt = 0; nt < 4; nt++)
      #pragma unroll
      for (int r = 0; r < 4; r++)
        ps[g * 4 + r][nt * 16 + n] = p[nt][r];
    bf16x8 pa[2];
    #pragma unroll
    for (int ks = 0; ks < 2; ks++){
      const f32x4* pr = reinterpret_cast<const f32x4*>(&ps[n][ks * 32 + g * 8]);
      f32x4 f0 = pr[0], f1 = pr[1];
      bf16x8 t;
      t[0] = (short)f2bf(f0[0]); t[1] = (short)f2bf(f0[1]);
      t[2] = (short)f2bf(f0[2]); t[3] = (short)f2bf(f0[3]);
      t[4] = (short)f2bf(f1[0]); t[5] = (short)f2bf(f1[1]);
      t[6] = (short)f2bf(f1[2]); t[7] = (short)f2bf(f1[3]);
      pa[ks] = t;
    }
    // O^T += P * V^T  (B-operand: col = c-local, k = j-local)
    #pragma unroll
    for (int ct = 0; ct < 16; ct++){
      long vb = ((long)b * NC + c0w + ct * 16 + n) * HW + j0 + g * 8;
      bf16x8 bv0 = *reinterpret_cast<const bf16x8*>(vv + vb);
      bf16x8 bv1 = *reinterpret_cast<const bf16x8*>(vv + vb + 32);
      acc[ct] = __builtin_amdgcn_mfma_f32_16x16x32_bf16(pa[0], bv0, acc[ct], 0, 0, 0);
      acc[ct] = __builtin_amdgcn_mfma_f32_16x16x32_bf16(pa[1], bv1, acc[ct], 0, 0, 0);
    }
  }
  // normalize, store O^T bf16 [b][pix][c]
  float rl[4];
  #pragma unroll
  for (int r = 0; r < 4; r++) rl[r] = 1.f / lrow[r];
  #pragma unroll
  for (int ct = 0; ct < 16; ct++){
    #pragma unroll
    for (int r = 0; r < 4; r++){
      long ob = ((long)b * HW + i0 + g * 4 + r) * NC + c0w + ct * 16 + n;
      Ot[ob] = f2bf(acc[ct][r] * rl[r]);
    }
  }
}

// ---------------- epilogue: out = gamma * O + x (transpose O^T via LDS) ----------------
__global__ __launch_bounds__(256) void epi_kernel(
    const unsigned short* __restrict__ Ot, const float* __restrict__ x,
    const float* __restrict__ gamma, float* __restrict__ out)
{
  const int it = blockIdx.x;
  const int ct = blockIdx.y;
  const int b  = blockIdx.z;
  const int i0 = it * 64, c0 = ct * 64;
  const int tid = threadIdx.x;
  const int tx = tid & 63, ty = tid >> 6;
  __shared__ float ts[64][65];
  const float gm = gamma[0];
  #pragma unroll
  for (int u = 0; u < 16; u++){
    int il = ty * 16 + u;
    ts[il][tx] = bf2f(Ot[((long)b * HW + i0 + il) * NC + c0 + tx]);
  }
  __syncthreads();
  #pragma unroll
  for (int u = 0; u < 16; u++){
    int cl = ty * 16 + u;
    long idx = ((long)b * NC + c0 + cl) * HW + i0 + tx;
    out[idx] = fmaf(gm, ts[tx][cl], x[idx]);
  }
}

extern "C" void kernel_launch(void* const* d_in, const int* in_sizes, int n_in,
                              void* d_out, int out_size, void* d_ws, size_t ws_size,
                              hipStream_t stream)
{
  const float* x  = (const float*)d_in[0];
  const float* Wq = (const float*)d_in[1];
  const float* bq = (const float*)d_in[2];
  const float* Wk = (const float*)d_in[3];
  const float* bk = (const float*)d_in[4];
  const float* Wv = (const float*)d_in[5];
  const float* bv = (const float*)d_in[6];
  const float* gamma = (const float*)d_in[7];
  float* out = (float*)d_out;

  char* ws = (char*)d_ws;
  const size_t SZ_QK = (size_t)NB * HW * 64 * sizeof(unsigned short);  // 2 MB each
  const size_t SZ_V  = (size_t)NB * NC * HW * sizeof(unsigned short);  // 16 MB
  unsigned short* qhi = (unsigned short*)(ws);
  unsigned short* qlo = (unsigned short*)(ws + SZ_QK);
  unsigned short* khi = (unsigned short*)(ws + 2 * SZ_QK);
  unsigned short* klo = (unsigned short*)(ws + 3 * SZ_QK);
  unsigned short* vv  = (unsigned short*)(ws + 4 * SZ_QK);
  unsigned short* Ot  = (unsigned short*)(ws + 4 * SZ_QK + SZ_V);
  // total ws use: 4*2MB + 16MB + 16MB = 40MB

  proj_kernel<<<dim3(32, 10, NB), dim3(256), 0, stream>>>(
      x, Wq, bq, Wk, bk, Wv, bv, qhi, qlo, khi, klo, vv);
  attn_kernel<<<dim3(NB * 128), dim3(256), 0, stream>>>(qhi, qlo, khi, klo, vv, Ot);
  epi_kernel<<<dim3(64, 8, NB), dim3(256), 0, stream>>>(Ot, x, gamma, out);
}

// Round 2
// 567.386 us; speedup vs baseline: 1.8382x; 1.8382x over previous
//
#include <hip/hip_runtime.h>
#include <hip/hip_bf16.h>

#define HW 4096
#define NC 512
#define NB 4

typedef float f32x4 __attribute__((ext_vector_type(4)));
typedef short bf16x8 __attribute__((ext_vector_type(8)));

#define GLOAD_LDS(g, s) __builtin_amdgcn_global_load_lds((const __attribute__((address_space(1))) void*)(g), (__attribute__((address_space(3))) void*)(s), 16, 0, 0)

__device__ __forceinline__ unsigned short f2bf(float f){
  unsigned int u = __builtin_bit_cast(unsigned int, f);
  u += 0x7FFFu + ((u >> 16) & 1u);
  return (unsigned short)(u >> 16);
}
__device__ __forceinline__ float bf2f(unsigned short h){
  unsigned int u = ((unsigned int)h) << 16;
  return __builtin_bit_cast(float, u);
}

// ---------------- projection: q/k (hi+lo split, transposed) + v ----------------
__global__ __launch_bounds__(256) void proj_kernel(
    const float* __restrict__ x,
    const float* __restrict__ Wq, const float* __restrict__ bq,
    const float* __restrict__ Wk, const float* __restrict__ bk,
    const float* __restrict__ Wv, const float* __restrict__ bv,
    unsigned short* __restrict__ qhi, unsigned short* __restrict__ qlo,
    unsigned short* __restrict__ khi, unsigned short* __restrict__ klo,
    unsigned short* __restrict__ vv)
{
  const int it = blockIdx.x;       // 128 pixels per block
  const int rg = blockIdx.y;
  const int b  = blockIdx.z;
  const int i0 = it * 128;
  const int tid = threadIdx.x;
  const int ix = tid & 63;
  const int rq = tid >> 6;

  __shared__ float xs[16][129];
  __shared__ float ts[128][65];

  const float* W; const float* bias; int rbase;
  if (rg == 0)      { W = Wq; bias = bq; rbase = 0; }
  else if (rg == 1) { W = Wk; bias = bk; rbase = 0; }
  else              { W = Wv; bias = bv; rbase = (rg - 2) * 64; }

  float acc0[16], acc1[16];
  #pragma unroll
  for (int rr = 0; rr < 16; rr++){ acc0[rr] = 0.f; acc1[rr] = 0.f; }

  for (int c0 = 0; c0 < NC; c0 += 16){
    __syncthreads();
    #pragma unroll
    for (int u = 0; u < 8; u++){
      int idx = u * 256 + tid;
      int row = idx >> 7, col = idx & 127;
      xs[row][col] = x[((long)b * NC + c0 + row) * HW + i0 + col];
    }
    __syncthreads();
    float xq0[16], xq1[16];
    #pragma unroll
    for (int cc = 0; cc < 16; cc++){ xq0[cc] = xs[cc][ix]; xq1[cc] = xs[cc][ix + 64]; }
    #pragma unroll
    for (int rr = 0; rr < 16; rr++){
      const float* wrow = W + (long)(rbase + rq * 16 + rr) * NC + c0;
      #pragma unroll
      for (int q4 = 0; q4 < 4; q4++){
        f32x4 wv = *reinterpret_cast<const f32x4*>(wrow + q4 * 4);
        #pragma unroll
        for (int e = 0; e < 4; e++){
          acc0[rr] = fmaf(wv[e], xq0[q4 * 4 + e], acc0[rr]);
          acc1[rr] = fmaf(wv[e], xq1[q4 * 4 + e], acc1[rr]);
        }
      }
    }
  }

  if (rg >= 2){
    #pragma unroll
    for (int rr = 0; rr < 16; rr++){
      int r = rq * 16 + rr;
      float bb = bias[rbase + r];
      long base = ((long)b * NC + rbase + r) * HW + i0;
      vv[base + ix]      = f2bf(acc0[rr] + bb);
      vv[base + 64 + ix] = f2bf(acc1[rr] + bb);
    }
  } else {
    __syncthreads();
    #pragma unroll
    for (int rr = 0; rr < 16; rr++){
      int r = rq * 16 + rr;
      float bb = bias[r];
      ts[ix][r]      = acc0[rr] + bb;
      ts[ix + 64][r] = acc1[rr] + bb;
    }
    __syncthreads();
    unsigned short* hi = (rg == 0) ? qhi : khi;
    unsigned short* lo = (rg == 0) ? qlo : klo;
    #pragma unroll
    for (int u = 0; u < 32; u++){
      int il = rq * 32 + u;
      float v = ts[il][ix];
      unsigned short h = f2bf(v);
      float rem = v - bf2f(h);
      hi[((long)b * HW + i0 + il) * 64 + ix] = h;
      lo[((long)b * HW + i0 + il) * 64 + ix] = f2bf(rem);
    }
  }
}

// ---------------- flash attention (8 waves, LDS-staged K/V, async pipeline) ----------------
// grid = B*64 blocks, block = 512 (8 waves). Block covers 64 query rows.
// wave w: rg = w>>1 (16-row group), ch = w&1 (256-channel half).
// LDS: [0,32KB) K double-buffer (per buf: khi 8KB + klo 8KB, [64j][64d] XOR-8 swizzled)
//      [32KB,96KB) V tile [512c][64j] XOR-8 swizzled
//      [96KB,129KB) per-wave P scratch fp32 [8][16][68]
__global__ __launch_bounds__(512, 2) void attn_kernel(
    const unsigned short* __restrict__ qhi, const unsigned short* __restrict__ qlo,
    const unsigned short* __restrict__ khi, const unsigned short* __restrict__ klo,
    const unsigned short* __restrict__ vv, unsigned short* __restrict__ Ot)
{
  extern __shared__ char smem[];
  const int bx = blockIdx.x;
  const int b  = bx >> 6;
  const int it = bx & 63;
  const int tid = threadIdx.x;
  const int w = tid >> 6;
  const int lane = tid & 63;
  const int g = lane >> 4, n = lane & 15;
  const int rg = w >> 1, ch = w & 1;
  const int i0 = it * 64 + rg * 16;
  const int c0w = ch * 256;

  float* psw = (float*)(smem + 98304) + w * (16 * 68);

  const int kj = tid >> 3;                    // staging row for K
  const int kdblk = (tid & 7) ^ (kj & 7);     // pre-swizzled d-block
  const long kgbase = ((long)b * HW + kj) * 64 + kdblk * 8;
  char* kdst = smem + (w << 10);

  // ---- prologue: stage K[0] -> buf0, V[0]; load Q fragments
  GLOAD_LDS(khi + kgbase, kdst);
  GLOAD_LDS(klo + kgbase, kdst + 8192);
  #pragma unroll
  for (int r = 0; r < 8; r++){
    int ss = (r << 9) | tid;
    int c = ss >> 3;
    int jblk = (ss & 7) ^ (c & 7);
    long goff = (long)b * (NC * HW) + (long)c * HW + jblk * 8;
    GLOAD_LDS(vv + goff, smem + 32768 + (r << 13) + (w << 10));
  }

  bf16x8 aqh[2], aql[2];
  {
    long qb = ((long)b * HW + i0 + n) * 64 + g * 8;
    aqh[0] = *reinterpret_cast<const bf16x8*>(qhi + qb);
    aqh[1] = *reinterpret_cast<const bf16x8*>(qhi + qb + 32);
    aql[0] = *reinterpret_cast<const bf16x8*>(qlo + qb);
    aql[1] = *reinterpret_cast<const bf16x8*>(qlo + qb + 32);
  }

  f32x4 acc[16];
  #pragma unroll
  for (int t = 0; t < 16; t++) acc[t] = (f32x4){0.f, 0.f, 0.f, 0.f};
  float mrow[4], lrow[4];
  #pragma unroll
  for (int r = 0; r < 4; r++){ mrow[r] = -1e30f; lrow[r] = 0.f; }

  asm volatile("s_waitcnt vmcnt(0)" ::: "memory");
  __syncthreads();

  int cur = 0;
  for (int jt = 0; jt < 64; jt++){
    // 1. prefetch K[(jt+1)&63] into the other K buffer (2 issues, stay in flight)
    {
      long goff = kgbase + (long)(((jt + 1) & 63) << 6) * 64;
      char* dst = smem + ((cur ^ 1) << 14) + (w << 10);
      GLOAD_LDS(khi + goff, dst);
      GLOAD_LDS(klo + goff, dst + 8192);
    }
    // 2. QK from kbuf[cur] (hi/lo 3-term for fp32-grade logits)
    f32x4 sv4[4];
    {
      const char* kb0 = smem + (cur << 14);
      __builtin_amdgcn_s_setprio(1);
      #pragma unroll
      for (int nt = 0; nt < 4; nt++){
        int jl = nt * 16 + n;
        const char* kb = kb0 + jl * 128;
        int x0 = (g ^ (jl & 7)) << 4;
        int x1 = ((g + 4) ^ (jl & 7)) << 4;
        bf16x8 bh0 = *(const bf16x8*)(kb + x0);
        bf16x8 bh1 = *(const bf16x8*)(kb + x1);
        bf16x8 bl0 = *(const bf16x8*)(kb + 8192 + x0);
        bf16x8 bl1 = *(const bf16x8*)(kb + 8192 + x1);
        f32x4 sv = (f32x4){0.f, 0.f, 0.f, 0.f};
        sv = __builtin_amdgcn_mfma_f32_16x16x32_bf16(aqh[0], bh0, sv, 0, 0, 0);
        sv = __builtin_amdgcn_mfma_f32_16x16x32_bf16(aqh[1], bh1, sv, 0, 0, 0);
        sv = __builtin_amdgcn_mfma_f32_16x16x32_bf16(aql[0], bh0, sv, 0, 0, 0);
        sv = __builtin_amdgcn_mfma_f32_16x16x32_bf16(aql[1], bh1, sv, 0, 0, 0);
        sv = __builtin_amdgcn_mfma_f32_16x16x32_bf16(aqh[0], bl0, sv, 0, 0, 0);
        sv = __builtin_amdgcn_mfma_f32_16x16x32_bf16(aqh[1], bl1, sv, 0, 0, 0);
        sv4[nt] = sv;
      }
      __builtin_amdgcn_s_setprio(0);
    }
    // 3. online softmax
    float mnew[4]; int upd = 0;
    #pragma unroll
    for (int r = 0; r < 4; r++){
      float t = fmaxf(fmaxf(sv4[0][r], sv4[1][r]), fmaxf(sv4[2][r], sv4[3][r]));
      t = fmaxf(t, __shfl_xor(t, 1));
      t = fmaxf(t, __shfl_xor(t, 2));
      t = fmaxf(t, __shfl_xor(t, 4));
      t = fmaxf(t, __shfl_xor(t, 8));
      mnew[r] = fmaxf(mrow[r], t);
      upd |= (mnew[r] > mrow[r]) ? 1 : 0;
    }
    if (__any(upd)){
      #pragma unroll
      for (int r = 0; r < 4; r++){
        float sc = __expf(mrow[r] - mnew[r]);
        lrow[r] *= sc;
        mrow[r] = mnew[r];
        #pragma unroll
        for (int t = 0; t < 16; t++) acc[t][r] *= sc;
      }
    }
    float p[4][4];
    #pragma unroll
    for (int nt = 0; nt < 4; nt++)
      #pragma unroll
      for (int r = 0; r < 4; r++)
        p[nt][r] = __expf(sv4[nt][r] - mrow[r]);
    #pragma unroll
    for (int r = 0; r < 4; r++){
      float rs = (p[0][r] + p[1][r]) + (p[2][r] + p[3][r]);
      rs += __shfl_xor(rs, 1);
      rs += __shfl_xor(rs, 2);
      rs += __shfl_xor(rs, 4);
      rs += __shfl_xor(rs, 8);
      lrow[r] += rs;
    }
    // 4. P tile -> per-wave LDS (fp32), reload in A-fragment layout, cvt bf16
    #pragma unroll
    for (int nt = 0; nt < 4; nt++)
      #pragma unroll
      for (int r = 0; r < 4; r++)
        psw[(g * 4 + r) * 68 + nt * 16 + n] = p[nt][r];
    bf16x8 pa[2];
    #pragma unroll
    for (int ks = 0; ks < 2; ks++){
      const f32x4* pr = reinterpret_cast<const f32x4*>(&psw[n * 68 + ks * 32 + g * 8]);
      f32x4 f0 = pr[0], f1 = pr[1];
      bf16x8 t;
      t[0] = (short)f2bf(f0[0]); t[1] = (short)f2bf(f0[1]);
      t[2] = (short)f2bf(f0[2]); t[3] = (short)f2bf(f0[3]);
      t[4] = (short)f2bf(f1[0]); t[5] = (short)f2bf(f1[1]);
      t[6] = (short)f2bf(f1[2]); t[7] = (short)f2bf(f1[3]);
      pa[ks] = t;
    }
    // 5. wait V[jt] landed (K[jt+1] still in flight), sync all waves
    asm volatile("s_waitcnt vmcnt(2)" ::: "memory");
    __syncthreads();
    // 6. PV from V LDS tile
    {
      const char* vb0 = smem + 32768 + (c0w + n) * 128;
      __builtin_amdgcn_s_setprio(1);
      #pragma unroll
      for (int ct = 0; ct < 16; ct++){
        int cl = c0w + ct * 16 + n;
        const char* vb = vb0 + ct * 2048;
        int x0 = (g ^ (cl & 7)) << 4;
        int x1 = ((g + 4) ^ (cl & 7)) << 4;
        bf16x8 bv0 = *(const bf16x8*)(vb + x0);
        bf16x8 bv1 = *(const bf16x8*)(vb + x1);
        acc[ct] = __builtin_amdgcn_mfma_f32_16x16x32_bf16(pa[0], bv0, acc[ct], 0, 0, 0);
        acc[ct] = __builtin_amdgcn_mfma_f32_16x16x32_bf16(pa[1], bv1, acc[ct], 0, 0, 0);
      }
      __builtin_amdgcn_s_setprio(0);
    }
    // 7. drain K prefetch, sync (all waves done reading vbuf), then refill V
    asm volatile("s_waitcnt vmcnt(0)" ::: "memory");
    __syncthreads();
    if (jt < 63){
      int j0v = (jt + 1) << 6;
      #pragma unroll
      for (int r = 0; r < 8; r++){
        int ss = (r << 9) | tid;
        int c = ss >> 3;
        int jblk = (ss & 7) ^ (c & 7);
        long goff = (long)b * (NC * HW) + (long)c * HW + j0v + jblk * 8;
        GLOAD_LDS(vv + goff, smem + 32768 + (r << 13) + (w << 10));
      }
    }
    cur ^= 1;
  }

  // normalize, store O^T bf16 [b][pix][c]
  float rl[4];
  #pragma unroll
  for (int r = 0; r < 4; r++) rl[r] = 1.f / lrow[r];
  #pragma unroll
  for (int ct = 0; ct < 16; ct++){
    #pragma unroll
    for (int r = 0; r < 4; r++){
      long ob = ((long)b * HW + i0 + g * 4 + r) * NC + c0w + ct * 16 + n;
      Ot[ob] = f2bf(acc[ct][r] * rl[r]);
    }
  }
}

// ---------------- epilogue: out = gamma * O + x ----------------
__global__ __launch_bounds__(256) void epi_kernel(
    const unsigned short* __restrict__ Ot, const float* __restrict__ x,
    const float* __restrict__ gamma, float* __restrict__ out)
{
  const int it = blockIdx.x;
  const int ct = blockIdx.y;
  const int b  = blockIdx.z;
  const int i0 = it * 64, c0 = ct * 64;
  const int tid = threadIdx.x;
  const int tx = tid & 63, ty = tid >> 6;
  __shared__ float ts[64][65];
  const float gm = gamma[0];
  #pragma unroll
  for (int u = 0; u < 16; u++){
    int il = ty * 16 + u;
    ts[il][tx] = bf2f(Ot[((long)b * HW + i0 + il) * NC + c0 + tx]);
  }
  __syncthreads();
  #pragma unroll
  for (int u = 0; u < 16; u++){
    int cl = ty * 16 + u;
    long idx = ((long)b * NC + c0 + cl) * HW + i0 + tx;
    out[idx] = fmaf(gm, ts[tx][cl], x[idx]);
  }
}

extern "C" void kernel_launch(void* const* d_in, const int* in_sizes, int n_in,
                              void* d_out, int out_size, void* d_ws, size_t ws_size,
                              hipStream_t stream)
{
  const float* x  = (const float*)d_in[0];
  const float* Wq = (const float*)d_in[1];
  const float* bq = (const float*)d_in[2];
  const float* Wk = (const float*)d_in[3];
  const float* bk = (const float*)d_in[4];
  const float* Wv = (const float*)d_in[5];
  const float* bv = (const float*)d_in[6];
  const float* gamma = (const float*)d_in[7];
  float* out = (float*)d_out;

  char* ws = (char*)d_ws;
  const size_t SZ_QK = (size_t)NB * HW * 64 * sizeof(unsigned short);  // 2 MB each
  const size_t SZ_V  = (size_t)NB * NC * HW * sizeof(unsigned short);  // 16 MB
  unsigned short* qhi = (unsigned short*)(ws);
  unsigned short* qlo = (unsigned short*)(ws + SZ_QK);
  unsigned short* khi = (unsigned short*)(ws + 2 * SZ_QK);
  unsigned short* klo = (unsigned short*)(ws + 3 * SZ_QK);
  unsigned short* vv  = (unsigned short*)(ws + 4 * SZ_QK);
  unsigned short* Ot  = (unsigned short*)(ws + 4 * SZ_QK + SZ_V);

  proj_kernel<<<dim3(32, 10, NB), dim3(256), 0, stream>>>(
      x, Wq, bq, Wk, bk, Wv, bv, qhi, qlo, khi, klo, vv);

  const int SMEM = 133120;  // 32KB K dbuf + 64KB V + 33KB P scratch
  hipFuncSetAttribute((const void*)attn_kernel,
                      hipFuncAttributeMaxDynamicSharedMemorySize, SMEM);
  attn_kernel<<<dim3(NB * 64), dim3(512), SMEM, stream>>>(qhi, qlo, khi, klo, vv, Ot);

  epi_kernel<<<dim3(64, 8, NB), dim3(256), 0, stream>>>(Ot, x, gamma, out);
}

// Round 3
// 283.506 us; speedup vs baseline: 3.6788x; 2.0013x over previous
//
#include <hip/hip_runtime.h>
#include <hip/hip_bf16.h>

#define HW 4096
#define NC 512
#define NB 4

typedef float f32x4 __attribute__((ext_vector_type(4)));
typedef short bf16x8 __attribute__((ext_vector_type(8)));
typedef unsigned short ushort_t;

#define GLOAD_LDS(g, s) __builtin_amdgcn_global_load_lds((const __attribute__((address_space(1))) void*)(g), (__attribute__((address_space(3))) void*)(s), 16, 0, 0)

__device__ __forceinline__ unsigned short f2bf(float f){
  unsigned int u = __builtin_bit_cast(unsigned int, f);
  u += 0x7FFFu + ((u >> 16) & 1u);
  return (unsigned short)(u >> 16);
}
__device__ __forceinline__ float bf2f(unsigned short h){
  unsigned int u = ((unsigned int)h) << 16;
  return __builtin_bit_cast(float, u);
}

// ---------------- W -> bf16 hi (+lo for q/k rows 0..127) ----------------
__global__ __launch_bounds__(256) void wsplit_kernel(
    const float* __restrict__ Wq, const float* __restrict__ Wk,
    const float* __restrict__ Wv, ushort_t* __restrict__ wh, ushort_t* __restrict__ wl)
{
  long e = ((long)blockIdx.x * 256 + threadIdx.x) * 8;  // grid 160 -> 640*512 elems
  int r = (int)(e >> 9), c = (int)(e & 511);
  const float* src = (r < 64)  ? Wq + (long)r * 512 + c
                   : (r < 128) ? Wk + (long)(r - 64) * 512 + c
                               : Wv + (long)(r - 128) * 512 + c;
  f32x4 v0 = *reinterpret_cast<const f32x4*>(src);
  f32x4 v1 = *reinterpret_cast<const f32x4*>(src + 4);
  ushort_t h[8], l[8];
  #pragma unroll
  for (int j = 0; j < 4; j++){ h[j] = f2bf(v0[j]); l[j] = f2bf(v0[j] - bf2f(h[j])); }
  #pragma unroll
  for (int j = 0; j < 4; j++){ h[4+j] = f2bf(v1[j]); l[4+j] = f2bf(v1[j] - bf2f(h[4+j])); }
  *reinterpret_cast<bf16x8*>(wh + e) = *reinterpret_cast<bf16x8*>(h);
  if (r < 128) *reinterpret_cast<bf16x8*>(wl + e) = *reinterpret_cast<bf16x8*>(l);
}

// ---------------- x [b][c][px] fp32 -> xt hi/lo [b][px][c] bf16 ----------------
__global__ __launch_bounds__(256) void split_kernel(
    const float* __restrict__ x, ushort_t* __restrict__ xth, ushort_t* __restrict__ xtl)
{
  const int i0 = blockIdx.x * 64;
  const int c0 = blockIdx.y * 64;
  const int b  = blockIdx.z;
  const int tid = threadIdx.x;
  const int tx = tid & 63, ty = tid >> 6;
  __shared__ float ts[64][65];
  #pragma unroll
  for (int u = 0; u < 16; u++){
    int cl = ty * 16 + u;
    ts[cl][tx] = x[((long)b * NC + c0 + cl) * HW + i0 + tx];
  }
  __syncthreads();
  const int px = tid >> 2;
  const int cs = (tid & 3) * 16;
  ushort_t h[16], l[16];
  #pragma unroll
  for (int e = 0; e < 16; e++){
    float v = ts[cs + e][px];
    h[e] = f2bf(v);
    l[e] = f2bf(v - bf2f(h[e]));
  }
  long base = ((long)b * HW + i0 + px) * 512 + c0 + cs;
  *reinterpret_cast<bf16x8*>(xth + base)     = *reinterpret_cast<bf16x8*>(h);
  *reinterpret_cast<bf16x8*>(xth + base + 8) = *reinterpret_cast<bf16x8*>(h + 8);
  *reinterpret_cast<bf16x8*>(xtl + base)     = *reinterpret_cast<bf16x8*>(l);
  *reinterpret_cast<bf16x8*>(xtl + base + 8) = *reinterpret_cast<bf16x8*>(l + 8);
}

// ---------------- MFMA projection GEMM ----------------
// grid (32 pxtiles of 128, 5 rgroups, NB), block 256 (4 waves: wy px-half, wx r-half).
// rgroup 0: rows 0..127 = [q|k] (A=xt, B=W, 3-term, D=[px,r])
// rgroup 1..4: v rows (rg-1)*128.. (A=W, B=xt, 2-term, D=[c,px])
// LDS 64KB: buf[2][ xth 16KB | xtl 16KB ], [128px][64c] chunk-XOR-swizzled.
__global__ __launch_bounds__(256) void gemm_kernel(
    const ushort_t* __restrict__ xth, const ushort_t* __restrict__ xtl,
    const ushort_t* __restrict__ wh, const ushort_t* __restrict__ wl,
    const float* __restrict__ bq, const float* __restrict__ bk, const float* __restrict__ bv,
    ushort_t* __restrict__ qhi, ushort_t* __restrict__ qlo,
    ushort_t* __restrict__ khi, ushort_t* __restrict__ klo,
    ushort_t* __restrict__ vv)
{
  extern __shared__ char lds[];
  const int it = blockIdx.x;
  const int rg = blockIdx.y;
  const int b  = blockIdx.z;
  const int i0 = it * 128;
  const int tid = threadIdx.x;
  const int w = tid >> 6;
  const int lane = tid & 63;
  const int g = lane >> 4, n = lane & 15;
  const int wy = w >> 1, wx = w & 1;

  f32x4 acc[4][4];
  #pragma unroll
  for (int a = 0; a < 4; a++)
    #pragma unroll
    for (int m = 0; m < 4; m++) acc[a][m] = (f32x4){0.f, 0.f, 0.f, 0.f};

  // staging: per surface 128px x 64c bf16 = 16KB = 1024 chunks of 16B; 4 iters x 256 thr
  const long xrow = (long)b * HW + i0;

  auto stage = [&](int bsel, int c0s){
    char* dbase = lds + bsel * 32768 + (w << 10);
    #pragma unroll
    for (int u = 0; u < 4; u++){
      int idx = (u << 8) | tid;
      int px = idx >> 3;
      int chs = (idx & 7) ^ (px & 7);
      long go = (xrow + px) * 512 + c0s + chs * 8;
      GLOAD_LDS(xth + go, dbase + (u << 12));
      GLOAD_LDS(xtl + go, dbase + 16384 + (u << 12));
    }
  };

  stage(0, 0);
  asm volatile("s_waitcnt vmcnt(0)" ::: "memory");
  __syncthreads();

  int cur = 0;
  for (int t = 0; t < 8; t++){
    const int c0 = t << 6;
    // --- W fragment loads (global, L2-hot) issued first
    bf16x8 wfh[4][2], wfl[4][2];
    #pragma unroll
    for (int a = 0; a < 4; a++){
      long R = (long)(rg * 128 + wx * 64 + a * 16 + n) * 512 + c0 + g * 8;
      wfh[a][0] = *reinterpret_cast<const bf16x8*>(wh + R);
      wfh[a][1] = *reinterpret_cast<const bf16x8*>(wh + R + 32);
    }
    if (rg == 0){
      #pragma unroll
      for (int a = 0; a < 4; a++){
        long R = (long)(wx * 64 + a * 16 + n) * 512 + c0 + g * 8;
        wfl[a][0] = *reinterpret_cast<const bf16x8*>(wl + R);
        wfl[a][1] = *reinterpret_cast<const bf16x8*>(wl + R + 32);
      }
    }
    // --- prefetch next K-step into other buffer (stays in flight over compute)
    if (t < 7) stage(cur ^ 1, (t + 1) << 6);
    // --- xt fragments from LDS
    bf16x8 xh[4][2], xl[4][2];
    const char* buf = lds + cur * 32768;
    #pragma unroll
    for (int m = 0; m < 4; m++){
      int px = wy * 64 + m * 16 + n;
      const char* row = buf + px * 128;
      #pragma unroll
      for (int ks = 0; ks < 2; ks++){
        int off = (((ks << 2) | g) ^ (px & 7)) << 4;
        xh[m][ks] = *reinterpret_cast<const bf16x8*>(row + off);
        xl[m][ks] = *reinterpret_cast<const bf16x8*>(row + 16384 + off);
      }
    }
    // --- MFMA
    __builtin_amdgcn_s_setprio(1);
    if (rg == 0){
      #pragma unroll
      for (int a = 0; a < 4; a++)
        #pragma unroll
        for (int m = 0; m < 4; m++)
          #pragma unroll
          for (int ks = 0; ks < 2; ks++){
            acc[a][m] = __builtin_amdgcn_mfma_f32_16x16x32_bf16(xh[m][ks], wfh[a][ks], acc[a][m], 0, 0, 0);
            acc[a][m] = __builtin_amdgcn_mfma_f32_16x16x32_bf16(xl[m][ks], wfh[a][ks], acc[a][m], 0, 0, 0);
            acc[a][m] = __builtin_amdgcn_mfma_f32_16x16x32_bf16(xh[m][ks], wfl[a][ks], acc[a][m], 0, 0, 0);
          }
    } else {
      #pragma unroll
      for (int a = 0; a < 4; a++)
        #pragma unroll
        for (int m = 0; m < 4; m++)
          #pragma unroll
          for (int ks = 0; ks < 2; ks++){
            acc[a][m] = __builtin_amdgcn_mfma_f32_16x16x32_bf16(wfh[a][ks], xh[m][ks], acc[a][m], 0, 0, 0);
            acc[a][m] = __builtin_amdgcn_mfma_f32_16x16x32_bf16(wfh[a][ks], xl[m][ks], acc[a][m], 0, 0, 0);
          }
    }
    __builtin_amdgcn_s_setprio(0);
    asm volatile("s_waitcnt vmcnt(0)" ::: "memory");
    __syncthreads();
    cur ^= 1;
  }

  // ---------------- epilogue ----------------
  if (rg == 0){
    // D = [px, r]: row px = wy*64+m*16+g*4+reg, col r = wx*64+a*16+n
    ushort_t* hs = wx ? khi : qhi;
    ushort_t* ls = wx ? klo : qlo;
    const float* bias = wx ? bk : bq;
    #pragma unroll
    for (int a = 0; a < 4; a++){
      float bb = bias[a * 16 + n];
      #pragma unroll
      for (int m = 0; m < 4; m++){
        #pragma unroll
        for (int r4 = 0; r4 < 4; r4++){
          int px = wy * 64 + m * 16 + g * 4 + r4;
          float v = acc[a][m][r4] + bb;
          ushort_t h = f2bf(v);
          ushort_t l = f2bf(v - bf2f(h));
          long ad = (xrow + px) * 64 + a * 16 + n;
          hs[ad] = h;
          ls[ad] = l;
        }
      }
    }
  } else {
    // D = [c, px]: row c = wx*64+a*16+g*4+reg, col px = wy*64+m*16+n
    #pragma unroll
    for (int a = 0; a < 4; a++){
      #pragma unroll
      for (int r4 = 0; r4 < 4; r4++){
        int C = (rg - 1) * 128 + wx * 64 + a * 16 + g * 4 + r4;
        float bb = bv[C];
        #pragma unroll
        for (int m = 0; m < 4; m++){
          int px = wy * 64 + m * 16 + n;
          vv[((long)b * NC + C) * HW + i0 + px] = f2bf(acc[a][m][r4] + bb);
        }
      }
    }
  }
}

// ---------------- flash attention (unchanged from round 2) ----------------
__global__ __launch_bounds__(512, 2) void attn_kernel(
    const ushort_t* __restrict__ qhi, const ushort_t* __restrict__ qlo,
    const ushort_t* __restrict__ khi, const ushort_t* __restrict__ klo,
    const ushort_t* __restrict__ vv, ushort_t* __restrict__ Ot)
{
  extern __shared__ char smem[];
  const int bx = blockIdx.x;
  const int b  = bx >> 6;
  const int it = bx & 63;
  const int tid = threadIdx.x;
  const int w = tid >> 6;
  const int lane = tid & 63;
  const int g = lane >> 4, n = lane & 15;
  const int rg = w >> 1, ch = w & 1;
  const int i0 = it * 64 + rg * 16;
  const int c0w = ch * 256;

  float* psw = (float*)(smem + 98304) + w * (16 * 68);

  const int kj = tid >> 3;
  const int kdblk = (tid & 7) ^ (kj & 7);
  const long kgbase = ((long)b * HW + kj) * 64 + kdblk * 8;
  char* kdst = smem + (w << 10);

  GLOAD_LDS(khi + kgbase, kdst);
  GLOAD_LDS(klo + kgbase, kdst + 8192);
  #pragma unroll
  for (int r = 0; r < 8; r++){
    int ss = (r << 9) | tid;
    int c = ss >> 3;
    int jblk = (ss & 7) ^ (c & 7);
    long goff = (long)b * (NC * HW) + (long)c * HW + jblk * 8;
    GLOAD_LDS(vv + goff, smem + 32768 + (r << 13) + (w << 10));
  }

  bf16x8 aqh[2], aql[2];
  {
    long qb = ((long)b * HW + i0 + n) * 64 + g * 8;
    aqh[0] = *reinterpret_cast<const bf16x8*>(qhi + qb);
    aqh[1] = *reinterpret_cast<const bf16x8*>(qhi + qb + 32);
    aql[0] = *reinterpret_cast<const bf16x8*>(qlo + qb);
    aql[1] = *reinterpret_cast<const bf16x8*>(qlo + qb + 32);
  }

  f32x4 acc[16];
  #pragma unroll
  for (int t = 0; t < 16; t++) acc[t] = (f32x4){0.f, 0.f, 0.f, 0.f};
  float mrow[4], lrow[4];
  #pragma unroll
  for (int r = 0; r < 4; r++){ mrow[r] = -1e30f; lrow[r] = 0.f; }

  asm volatile("s_waitcnt vmcnt(0)" ::: "memory");
  __syncthreads();

  int cur = 0;
  for (int jt = 0; jt < 64; jt++){
    {
      long goff = kgbase + (long)(((jt + 1) & 63) << 6) * 64;
      char* dst = smem + ((cur ^ 1) << 14) + (w << 10);
      GLOAD_LDS(khi + goff, dst);
      GLOAD_LDS(klo + goff, dst + 8192);
    }
    f32x4 sv4[4];
    {
      const char* kb0 = smem + (cur << 14);
      __builtin_amdgcn_s_setprio(1);
      #pragma unroll
      for (int nt = 0; nt < 4; nt++){
        int jl = nt * 16 + n;
        const char* kb = kb0 + jl * 128;
        int x0 = (g ^ (jl & 7)) << 4;
        int x1 = ((g + 4) ^ (jl & 7)) << 4;
        bf16x8 bh0 = *(const bf16x8*)(kb + x0);
        bf16x8 bh1 = *(const bf16x8*)(kb + x1);
        bf16x8 bl0 = *(const bf16x8*)(kb + 8192 + x0);
        bf16x8 bl1 = *(const bf16x8*)(kb + 8192 + x1);
        f32x4 sv = (f32x4){0.f, 0.f, 0.f, 0.f};
        sv = __builtin_amdgcn_mfma_f32_16x16x32_bf16(aqh[0], bh0, sv, 0, 0, 0);
        sv = __builtin_amdgcn_mfma_f32_16x16x32_bf16(aqh[1], bh1, sv, 0, 0, 0);
        sv = __builtin_amdgcn_mfma_f32_16x16x32_bf16(aql[0], bh0, sv, 0, 0, 0);
        sv = __builtin_amdgcn_mfma_f32_16x16x32_bf16(aql[1], bh1, sv, 0, 0, 0);
        sv = __builtin_amdgcn_mfma_f32_16x16x32_bf16(aqh[0], bl0, sv, 0, 0, 0);
        sv = __builtin_amdgcn_mfma_f32_16x16x32_bf16(aqh[1], bl1, sv, 0, 0, 0);
        sv4[nt] = sv;
      }
      __builtin_amdgcn_s_setprio(0);
    }
    float mnew[4]; int upd = 0;
    #pragma unroll
    for (int r = 0; r < 4; r++){
      float t = fmaxf(fmaxf(sv4[0][r], sv4[1][r]), fmaxf(sv4[2][r], sv4[3][r]));
      t = fmaxf(t, __shfl_xor(t, 1));
      t = fmaxf(t, __shfl_xor(t, 2));
      t = fmaxf(t, __shfl_xor(t, 4));
      t = fmaxf(t, __shfl_xor(t, 8));
      mnew[r] = fmaxf(mrow[r], t);
      upd |= (mnew[r] > mrow[r]) ? 1 : 0;
    }
    if (__any(upd)){
      #pragma unroll
      for (int r = 0; r < 4; r++){
        float sc = __expf(mrow[r] - mnew[r]);
        lrow[r] *= sc;
        mrow[r] = mnew[r];
        #pragma unroll
        for (int t = 0; t < 16; t++) acc[t][r] *= sc;
      }
    }
    float p[4][4];
    #pragma unroll
    for (int nt = 0; nt < 4; nt++)
      #pragma unroll
      for (int r = 0; r < 4; r++)
        p[nt][r] = __expf(sv4[nt][r] - mrow[r]);
    #pragma unroll
    for (int r = 0; r < 4; r++){
      float rs = (p[0][r] + p[1][r]) + (p[2][r] + p[3][r]);
      rs += __shfl_xor(rs, 1);
      rs += __shfl_xor(rs, 2);
      rs += __shfl_xor(rs, 4);
      rs += __shfl_xor(rs, 8);
      lrow[r] += rs;
    }
    #pragma unroll
    for (int nt = 0; nt < 4; nt++)
      #pragma unroll
      for (int r = 0; r < 4; r++)
        psw[(g * 4 + r) * 68 + nt * 16 + n] = p[nt][r];
    bf16x8 pa[2];
    #pragma unroll
    for (int ks = 0; ks < 2; ks++){
      const f32x4* pr = reinterpret_cast<const f32x4*>(&psw[n * 68 + ks * 32 + g * 8]);
      f32x4 f0 = pr[0], f1 = pr[1];
      bf16x8 t;
      t[0] = (short)f2bf(f0[0]); t[1] = (short)f2bf(f0[1]);
      t[2] = (short)f2bf(f0[2]); t[3] = (short)f2bf(f0[3]);
      t[4] = (short)f2bf(f1[0]); t[5] = (short)f2bf(f1[1]);
      t[6] = (short)f2bf(f1[2]); t[7] = (short)f2bf(f1[3]);
      pa[ks] = t;
    }
    asm volatile("s_waitcnt vmcnt(2)" ::: "memory");
    __syncthreads();
    {
      const char* vb0 = smem + 32768 + (c0w + n) * 128;
      __builtin_amdgcn_s_setprio(1);
      #pragma unroll
      for (int ct = 0; ct < 16; ct++){
        int cl = c0w + ct * 16 + n;
        const char* vb = vb0 + ct * 2048;
        int x0 = (g ^ (cl & 7)) << 4;
        int x1 = ((g + 4) ^ (cl & 7)) << 4;
        bf16x8 bv0 = *(const bf16x8*)(vb + x0);
        bf16x8 bv1 = *(const bf16x8*)(vb + x1);
        acc[ct] = __builtin_amdgcn_mfma_f32_16x16x32_bf16(pa[0], bv0, acc[ct], 0, 0, 0);
        acc[ct] = __builtin_amdgcn_mfma_f32_16x16x32_bf16(pa[1], bv1, acc[ct], 0, 0, 0);
      }
      __builtin_amdgcn_s_setprio(0);
    }
    asm volatile("s_waitcnt vmcnt(0)" ::: "memory");
    __syncthreads();
    if (jt < 63){
      int j0v = (jt + 1) << 6;
      #pragma unroll
      for (int r = 0; r < 8; r++){
        int ss = (r << 9) | tid;
        int c = ss >> 3;
        int jblk = (ss & 7) ^ (c & 7);
        long goff = (long)b * (NC * HW) + (long)c * HW + j0v + jblk * 8;
        GLOAD_LDS(vv + goff, smem + 32768 + (r << 13) + (w << 10));
      }
    }
    cur ^= 1;
  }

  float rl[4];
  #pragma unroll
  for (int r = 0; r < 4; r++) rl[r] = 1.f / lrow[r];
  #pragma unroll
  for (int ct = 0; ct < 16; ct++){
    #pragma unroll
    for (int r = 0; r < 4; r++){
      long ob = ((long)b * HW + i0 + g * 4 + r) * NC + c0w + ct * 16 + n;
      Ot[ob] = f2bf(acc[ct][r] * rl[r]);
    }
  }
}

// ---------------- epilogue: out = gamma * O + x ----------------
__global__ __launch_bounds__(256) void epi_kernel(
    const ushort_t* __restrict__ Ot, const float* __restrict__ x,
    const float* __restrict__ gamma, float* __restrict__ out)
{
  const int it = blockIdx.x;
  const int ct = blockIdx.y;
  const int b  = blockIdx.z;
  const int i0 = it * 64, c0 = ct * 64;
  const int tid = threadIdx.x;
  const int tx = tid & 63, ty = tid >> 6;
  __shared__ float ts[64][65];
  const float gm = gamma[0];
  #pragma unroll
  for (int u = 0; u < 16; u++){
    int il = ty * 16 + u;
    ts[il][tx] = bf2f(Ot[((long)b * HW + i0 + il) * NC + c0 + tx]);
  }
  __syncthreads();
  #pragma unroll
  for (int u = 0; u < 16; u++){
    int cl = ty * 16 + u;
    long idx = ((long)b * NC + c0 + cl) * HW + i0 + tx;
    out[idx] = fmaf(gm, ts[tx][cl], x[idx]);
  }
}

extern "C" void kernel_launch(void* const* d_in, const int* in_sizes, int n_in,
                              void* d_out, int out_size, void* d_ws, size_t ws_size,
                              hipStream_t stream)
{
  const float* x  = (const float*)d_in[0];
  const float* Wq = (const float*)d_in[1];
  const float* bq = (const float*)d_in[2];
  const float* Wk = (const float*)d_in[3];
  const float* bk = (const float*)d_in[4];
  const float* Wv = (const float*)d_in[5];
  const float* bv = (const float*)d_in[6];
  const float* gamma = (const float*)d_in[7];
  float* out = (float*)d_out;

  char* ws = (char*)d_ws;
  const size_t MB = 1024 * 1024;
  ushort_t* xth = (ushort_t*)(ws);                 // 16 MB (aliased with Ot)
  ushort_t* xtl = (ushort_t*)(ws + 16 * MB);       // 16 MB
  ushort_t* qhi = (ushort_t*)(ws + 32 * MB);       // 2 MB
  ushort_t* qlo = (ushort_t*)(ws + 34 * MB);
  ushort_t* khi = (ushort_t*)(ws + 36 * MB);
  ushort_t* klo = (ushort_t*)(ws + 38 * MB);
  ushort_t* vv  = (ushort_t*)(ws + 40 * MB);       // 16 MB
  ushort_t* wh  = (ushort_t*)(ws + 56 * MB);       // 640 KB
  ushort_t* wl  = (ushort_t*)(ws + 56 * MB + 655360);  // 128 KB
  ushort_t* Ot  = xth;  // alias: xt dead after gemm_kernel, Ot written by attn

  wsplit_kernel<<<dim3(160), dim3(256), 0, stream>>>(Wq, Wk, Wv, wh, wl);
  split_kernel<<<dim3(64, 8, NB), dim3(256), 0, stream>>>(x, xth, xtl);

  const int GSMEM = 65536;
  hipFuncSetAttribute((const void*)gemm_kernel,
                      hipFuncAttributeMaxDynamicSharedMemorySize, GSMEM);
  gemm_kernel<<<dim3(32, 5, NB), dim3(256), GSMEM, stream>>>(
      xth, xtl, wh, wl, bq, bk, bv, qhi, qlo, khi, klo, vv);

  const int SMEM = 133120;
  hipFuncSetAttribute((const void*)attn_kernel,
                      hipFuncAttributeMaxDynamicSharedMemorySize, SMEM);
  attn_kernel<<<dim3(NB * 64), dim3(512), SMEM, stream>>>(qhi, qlo, khi, klo, vv, Ot);

  epi_kernel<<<dim3(64, 8, NB), dim3(256), 0, stream>>>(Ot, x, gamma, out);
}